// Round 2
// baseline (447.395 us; speedup 1.0000x reference)
//
#include <hip/hip_runtime.h>
#include <hip/hip_bf16.h>
#include <cstddef>
#include <cstdint>

// Problem constants (fixed by the reference)
#define N_TOK 16384     // B*S = 32*512
#define H_    2048
#define FP_   1024
#define SP_   1024
#define C_    2050      // 2 + FP + SP, prob_all row stride

// Fallback-path tile (old 128^2 kernel, used only if ws too small)
#define BM 128
#define BN 128
#define BK 64
#define KP 72           // padded stride for the FALLBACK fused kernel only

typedef short bf16x8 __attribute__((ext_vector_type(8)));  // 8 bf16 = 4 VGPRs
typedef float f32x4  __attribute__((ext_vector_type(4)));  // 4 fp32 acc

__device__ __forceinline__ unsigned pack_bf2(float a, float b) {
  __hip_bfloat16 x = __float2bfloat16(a);
  __hip_bfloat16 y = __float2bfloat16(b);
  unsigned short ux, uy;
  __builtin_memcpy(&ux, &x, 2);
  __builtin_memcpy(&uy, &y, 2);
  return (unsigned)ux | ((unsigned)uy << 16);
}

__device__ __forceinline__ unsigned short f2bf(float f) {
  __hip_bfloat16 h = __float2bfloat16(f);
  unsigned short u;
  __builtin_memcpy(&u, &h, 2);
  return u;
}

__device__ __forceinline__ float bf2f(unsigned short u) {
  unsigned v = (unsigned)u << 16;
  float f;
  __builtin_memcpy(&f, &v, 4);
  return f;
}

// ---------------------------------------------------------------------------
// FAST PATH kernel 1: fp32 -> bf16 pre-convert of X (rows 0..16383) and
// W_hcw|W_roo (rows 16384..18431) into d_ws, fusing the end-head dot
// (fp32-exact) into the X pass. One wave per row, 4 rows/block.  (unchanged)
// ---------------------------------------------------------------------------
__global__ __launch_bounds__(256) void convert_kernel(
    const float* __restrict__ X,
    const float* __restrict__ W_hcw, const float* __restrict__ W_roo,
    const float* __restrict__ W_end, const float* __restrict__ b_end,
    unsigned short* __restrict__ Xb, unsigned short* __restrict__ Wb,
    float* __restrict__ mat)
{
  const int wave = threadIdx.x >> 6;
  const int lane = threadIdx.x & 63;
  const int row  = (blockIdx.x << 2) + wave;
  const bool isX = row < N_TOK;
  const float* src;
  unsigned short* dst;
  if (isX) {
    src = X + (size_t)row * H_;
    dst = Xb + (size_t)row * H_;
  } else {
    const int m = row - N_TOK;
    src = (m < FP_) ? (W_hcw + (size_t)m * H_) : (W_roo + (size_t)(m - FP_) * H_);
    dst = Wb + (size_t)m * H_;
  }
  float s = 0.f;
#pragma unroll
  for (int i = 0; i < 8; ++i) {
    const int e = (lane << 2) + (i << 8);      // lane*4 + i*256: coalesced
    float4 v = *(const float4*)(src + e);
    uint2 p;
    p.x = pack_bf2(v.x, v.y);
    p.y = pack_bf2(v.z, v.w);
    *(uint2*)(dst + e) = p;
    if (isX) {                                  // wave-uniform branch
      float4 w = *(const float4*)(W_end + e);
      s += v.x * w.x + v.y * w.y + v.z * w.z + v.w * w.w;
    }
  }
  if (isX) {
#pragma unroll
    for (int o = 32; o; o >>= 1) s += __shfl_xor(s, o);
    if (lane == 0) mat[(size_t)row * C_] = s + b_end[0];
  }
}

// ---------------------------------------------------------------------------
// FAST PATH kernel 2: 256x256-tile, BK=64, 8-wave (2Mx4N) bf16 MFMA GEMM,
// 8-phase counted-vmcnt schedule (T3+T4) + setprio (T5). Double-buffered
// full K-tiles (64 KB each, 128 KB LDS total).
//
// Pipeline invariant: tiles t and t+1 always in flight (8 global_load_lds
// each => 16 outstanding per wave). At iteration top, `s_waitcnt vmcnt(8)`
// retires exactly tile t's loads; tile t+2 is issued into buf[t&1] only
// after the last phase barrier (all waves' ds_reads of that buffer retired,
// since each wave's lgkmcnt(0) precedes its pre-MFMA barrier). vmcnt is
// never drained to 0 in the main loop.
//
// Round-2 hardening vs round-1 (which hit an infra-level failure):
//   - #pragma unroll 1 on the K-tile loop (round-1 left it implicitly
//     unrollable: 32x body => codegen/compile blowup risk).
//   - sched_barrier(0) after each inline-asm waitcnt (pin the schedule).
// ---------------------------------------------------------------------------
__global__ __launch_bounds__(512) void gemm_8phase_kernel(
    const unsigned short* __restrict__ Xb, const unsigned short* __restrict__ Wb,
    const float* __restrict__ b_hcw, const float* __restrict__ b_roo,
    float* __restrict__ mat)
{
  __shared__ __align__(16) unsigned short As[2][256 * 64];   // 2 x 32 KB
  __shared__ __align__(16) unsigned short Bs[2][256 * 64];   // 2 x 32 KB

  const int c0 = blockIdx.x * 256;    // class-tile origin (8 tiles)
  const int n0 = blockIdx.y * 256;    // token-tile origin (64 tiles)
  const float* bias = (c0 < FP_) ? (b_hcw + c0) : (b_roo + (c0 - FP_));

  const int t    = threadIdx.x;       // 0..511
  const int wave = t >> 6;            // 0..7
  const int lane = t & 63;
  const int wr   = wave >> 2;         // 0..1 : M sub-tile (128 rows)
  const int wc   = wave & 3;          // 0..3 : N sub-tile (64 cols)
  const int quad = lane >> 4;
  const int l16  = lane & 15;
  const int sw   = l16 & 7;           // == row&7 for all fragment rows

  // staging map: thread t, iter r -> LDS row r*64 + (t>>3), chunk-pos t&7.
  // That slot must hold global chunk (t&7) ^ (row&7).  LDS dest is linear
  // in t (byte offset t*16), wave-uniform base + lane*16 as required.
  const int srow = t >> 3;                          // 0..63
  const int gch  = (t & 7) ^ (srow & 7);            // swizzled global chunk
  const unsigned short* gA = Xb + (size_t)(n0 + srow) * H_ + (gch << 3);
  const unsigned short* gB = Wb + (size_t)(c0 + srow) * H_ + (gch << 3);
  const int lds_off = srow * 64 + ((t & 7) << 3);   // element offset

  auto stage = [&](int buf, int k0) {               // 8 loads = one K-tile
#pragma unroll
    for (int r = 0; r < 4; ++r) {
      __builtin_amdgcn_global_load_lds(
          (const __attribute__((address_space(1))) unsigned int*)(gA + (size_t)(r * 64) * H_ + k0),
          (__attribute__((address_space(3))) unsigned int*)(&As[buf][r * 4096 + lds_off]),
          16, 0, 0);
      __builtin_amdgcn_global_load_lds(
          (const __attribute__((address_space(1))) unsigned int*)(gB + (size_t)(r * 64) * H_ + k0),
          (__attribute__((address_space(3))) unsigned int*)(&Bs[buf][r * 4096 + lds_off]),
          16, 0, 0);
    }
  };

  f32x4 acc[8][4];
#pragma unroll
  for (int i = 0; i < 8; ++i)
#pragma unroll
    for (int j = 0; j < 4; ++j)
#pragma unroll
      for (int r = 0; r < 4; ++r) acc[i][j][r] = 0.f;

  const int arow = wr * 128 + l16;    // + i*16
  const int brow = wc * 64 + l16;     // + j*16

  // prologue: tiles 0 and 1 in flight
  stage(0, 0);
  stage(1, 64);

  bf16x8 a[4][2], b[2][2];

#pragma unroll 1
  for (int tk = 0; tk < 32; ++tk) {
    const int cur = tk & 1;
    if (tk < 31) { asm volatile("s_waitcnt vmcnt(8)" ::: "memory"); }
    else         { asm volatile("s_waitcnt vmcnt(0)" ::: "memory"); }
    __builtin_amdgcn_sched_barrier(0);
    __builtin_amdgcn_s_barrier();     // tile tk staged for ALL waves

    const unsigned short* A_ = &As[cur][0];
    const unsigned short* B_ = &Bs[cur][0];

    // ---- Phase 0: ld A[i0..3], B[j0..1]; MFMA quad (i0..3)x(j0..1) --------
#pragma unroll
    for (int i = 0; i < 4; ++i)
#pragma unroll
      for (int kk = 0; kk < 2; ++kk)
        a[i][kk] = *(const bf16x8*)&A_[(arow + i * 16) * 64 + ((((kk << 2) + quad) ^ sw) << 3)];
#pragma unroll
    for (int j = 0; j < 2; ++j)
#pragma unroll
      for (int kk = 0; kk < 2; ++kk)
        b[j][kk] = *(const bf16x8*)&B_[(brow + j * 16) * 64 + ((((kk << 2) + quad) ^ sw) << 3)];
    __builtin_amdgcn_s_barrier();
    asm volatile("s_waitcnt lgkmcnt(0)" ::: "memory");
    __builtin_amdgcn_sched_barrier(0);
    __builtin_amdgcn_s_setprio(1);
#pragma unroll
    for (int i = 0; i < 4; ++i)
#pragma unroll
      for (int j = 0; j < 2; ++j)
#pragma unroll
        for (int kk = 0; kk < 2; ++kk)
          acc[i][j] = __builtin_amdgcn_mfma_f32_16x16x32_bf16(a[i][kk], b[j][kk], acc[i][j], 0, 0, 0);
    __builtin_amdgcn_s_setprio(0);
    __builtin_amdgcn_s_barrier();

    // ---- Phase 1: ld B[j2..3]; MFMA quad (i0..3)x(j2..3) ------------------
#pragma unroll
    for (int j = 0; j < 2; ++j)
#pragma unroll
      for (int kk = 0; kk < 2; ++kk)
        b[j][kk] = *(const bf16x8*)&B_[(brow + (j + 2) * 16) * 64 + ((((kk << 2) + quad) ^ sw) << 3)];
    __builtin_amdgcn_s_barrier();
    asm volatile("s_waitcnt lgkmcnt(0)" ::: "memory");
    __builtin_amdgcn_sched_barrier(0);
    __builtin_amdgcn_s_setprio(1);
#pragma unroll
    for (int i = 0; i < 4; ++i)
#pragma unroll
      for (int j = 0; j < 2; ++j)
#pragma unroll
        for (int kk = 0; kk < 2; ++kk)
          acc[i][j + 2] = __builtin_amdgcn_mfma_f32_16x16x32_bf16(a[i][kk], b[j][kk], acc[i][j + 2], 0, 0, 0);
    __builtin_amdgcn_s_setprio(0);
    __builtin_amdgcn_s_barrier();

    // ---- Phase 2: ld A[i4..7]; MFMA quad (i4..7)x(j2..3) ------------------
#pragma unroll
    for (int i = 0; i < 4; ++i)
#pragma unroll
      for (int kk = 0; kk < 2; ++kk)
        a[i][kk] = *(const bf16x8*)&A_[(arow + (i + 4) * 16) * 64 + ((((kk << 2) + quad) ^ sw) << 3)];
    __builtin_amdgcn_s_barrier();
    asm volatile("s_waitcnt lgkmcnt(0)" ::: "memory");
    __builtin_amdgcn_sched_barrier(0);
    __builtin_amdgcn_s_setprio(1);
#pragma unroll
    for (int i = 0; i < 4; ++i)
#pragma unroll
      for (int j = 0; j < 2; ++j)
#pragma unroll
        for (int kk = 0; kk < 2; ++kk)
          acc[i + 4][j + 2] = __builtin_amdgcn_mfma_f32_16x16x32_bf16(a[i][kk], b[j][kk], acc[i + 4][j + 2], 0, 0, 0);
    __builtin_amdgcn_s_setprio(0);
    __builtin_amdgcn_s_barrier();

    // ---- Phase 3: ld B[j0..1]; MFMA quad (i4..7)x(j0..1) ------------------
#pragma unroll
    for (int j = 0; j < 2; ++j)
#pragma unroll
      for (int kk = 0; kk < 2; ++kk)
        b[j][kk] = *(const bf16x8*)&B_[(brow + j * 16) * 64 + ((((kk << 2) + quad) ^ sw) << 3)];
    __builtin_amdgcn_s_barrier();
    asm volatile("s_waitcnt lgkmcnt(0)" ::: "memory");
    __builtin_amdgcn_sched_barrier(0);
    __builtin_amdgcn_s_setprio(1);
#pragma unroll
    for (int i = 0; i < 4; ++i)
#pragma unroll
      for (int j = 0; j < 2; ++j)
#pragma unroll
        for (int kk = 0; kk < 2; ++kk)
          acc[i + 4][j] = __builtin_amdgcn_mfma_f32_16x16x32_bf16(a[i][kk], b[j][kk], acc[i + 4][j], 0, 0, 0);
    __builtin_amdgcn_s_setprio(0);
    __builtin_amdgcn_s_barrier();     // all reads of buf[cur] retired

    // issue tile tk+2 into buf[cur] (now free); stays in flight across
    // the next iteration's barriers (counted vmcnt, never drained to 0).
    if (tk < 30) stage(cur, (tk + 2) << 6);
  }

  // C/D layout: col=lane&15, row=quad*4+reg (m89-verified). Store bf16.
  float bj[4];
#pragma unroll
  for (int j = 0; j < 4; ++j) bj[j] = bias[wc * 64 + j * 16 + l16];
#pragma unroll
  for (int i = 0; i < 8; ++i) {
#pragma unroll
    for (int r = 0; r < 4; ++r) {
      const int row = n0 + wr * 128 + i * 16 + quad * 4 + r;
      unsigned short* dst =
          (unsigned short*)(mat + (size_t)row * C_ + 4) + c0 + wc * 64 + l16;
#pragma unroll
      for (int j = 0; j < 4; ++j) dst[j * 16] = f2bf(acc[i][j][r] + bj[j]);
    }
  }
}

// ---------------------------------------------------------------------------
// FALLBACK kernels (used only if ws_size is too small). Same bf16-logit
// output convention as the fast path so one epilogue serves both.
// ---------------------------------------------------------------------------
__global__ __launch_bounds__(256) void end_head_kernel(
    const float* __restrict__ X, const float* __restrict__ W_end,
    const float* __restrict__ b_end, float* __restrict__ mat)
{
  const int wave = threadIdx.x >> 6;
  const int lane = threadIdx.x & 63;
  const int n = (blockIdx.x << 2) + wave;
  const float* x = X + (size_t)n * H_;
  float s = 0.f;
#pragma unroll
  for (int i = 0; i < 8; ++i) {
    const int e = (lane + (i << 6)) << 2;
    float4 xv = *(const float4*)(x + e);
    float4 wv = *(const float4*)(W_end + e);
    s += xv.x * wv.x + xv.y * wv.y + xv.z * wv.z + xv.w * wv.w;
  }
#pragma unroll
  for (int o = 32; o; o >>= 1) s += __shfl_xor(s, o);
  if (lane == 0) mat[(size_t)n * C_] = s + b_end[0];
}

__global__ __launch_bounds__(256) void logits_gemm_fused(
    const float* __restrict__ X,
    const float* __restrict__ W_hcw, const float* __restrict__ W_roo,
    const float* __restrict__ b_hcw, const float* __restrict__ b_roo,
    float* __restrict__ mat)
{
  __shared__ __align__(16) unsigned short As[BM * KP];
  __shared__ __align__(16) unsigned short Bs[BN * KP];

  const int c0 = blockIdx.x * BN;
  const int n0 = blockIdx.y * BM;
  const float* Wbase = (c0 < FP_) ? (W_hcw + (size_t)c0 * H_)
                                  : (W_roo + (size_t)(c0 - FP_) * H_);
  const float* bias  = (c0 < FP_) ? (b_hcw + c0) : (b_roo + (c0 - FP_));

  const int t    = threadIdx.x;
  const int wave = t >> 6;
  const int lane = t & 63;
  const int wy   = wave >> 1;
  const int wx   = wave & 1;
  const int quad = lane >> 4;
  const int l16  = lane & 15;
  const int tq = t & 3;
  const int tr = t >> 2;

  f32x4 acc[4][4];
#pragma unroll
  for (int i = 0; i < 4; ++i)
#pragma unroll
    for (int j = 0; j < 4; ++j)
#pragma unroll
      for (int r = 0; r < 4; ++r) acc[i][j][r] = 0.f;

  for (int k0 = 0; k0 < H_; k0 += BK) {
#pragma unroll
    for (int p = 0; p < 2; ++p) {
      const int row = tr + (p << 6);
      const float4* xs = (const float4*)(X + (size_t)(n0 + row) * H_ + k0 + (tq << 4));
      const float4* ws = (const float4*)(Wbase + (size_t)row * H_ + k0 + (tq << 4));
      float4 x0 = xs[0], x1 = xs[1], x2 = xs[2], x3 = xs[3];
      float4 w0 = ws[0], w1 = ws[1], w2 = ws[2], w3 = ws[3];
      uint4 ua0 = {pack_bf2(x0.x, x0.y), pack_bf2(x0.z, x0.w),
                   pack_bf2(x1.x, x1.y), pack_bf2(x1.z, x1.w)};
      uint4 ua1 = {pack_bf2(x2.x, x2.y), pack_bf2(x2.z, x2.w),
                   pack_bf2(x3.x, x3.y), pack_bf2(x3.z, x3.w)};
      uint4 ub0 = {pack_bf2(w0.x, w0.y), pack_bf2(w0.z, w0.w),
                   pack_bf2(w1.x, w1.y), pack_bf2(w1.z, w1.w)};
      uint4 ub1 = {pack_bf2(w2.x, w2.y), pack_bf2(w2.z, w2.w),
                   pack_bf2(w3.x, w3.y), pack_bf2(w3.z, w3.w)};
      *(uint4*)&As[row * KP + (tq << 4)]     = ua0;
      *(uint4*)&As[row * KP + (tq << 4) + 8] = ua1;
      *(uint4*)&Bs[row * KP + (tq << 4)]     = ub0;
      *(uint4*)&Bs[row * KP + (tq << 4) + 8] = ub1;
    }
    __syncthreads();
#pragma unroll
    for (int kk = 0; kk < 2; ++kk) {
      bf16x8 af[4], bfr[4];
#pragma unroll
      for (int i = 0; i < 4; ++i)
        af[i] = *(const bf16x8*)&As[(wy * 64 + i * 16 + l16) * KP + kk * 32 + quad * 8];
#pragma unroll
      for (int j = 0; j < 4; ++j)
        bfr[j] = *(const bf16x8*)&Bs[(wx * 64 + j * 16 + l16) * KP + kk * 32 + quad * 8];
#pragma unroll
      for (int i = 0; i < 4; ++i)
#pragma unroll
        for (int j = 0; j < 4; ++j)
          acc[i][j] = __builtin_amdgcn_mfma_f32_16x16x32_bf16(af[i], bfr[j], acc[i][j], 0, 0, 0);
    }
    __syncthreads();
  }

  float bj[4];
#pragma unroll
  for (int j = 0; j < 4; ++j) bj[j] = bias[wx * 64 + j * 16 + l16];
#pragma unroll
  for (int i = 0; i < 4; ++i) {
#pragma unroll
    for (int r = 0; r < 4; ++r) {
      const int row = n0 + wy * 64 + i * 16 + quad * 4 + r;
      unsigned short* dst =
          (unsigned short*)(mat + (size_t)row * C_ + 4) + c0 + wx * 64 + l16;
#pragma unroll
      for (int j = 0; j < 4; ++j) dst[j * 16] = f2bf(acc[i][j][r] + bj[j]);
    }
  }
}

// ---------------------------------------------------------------------------
// Epilogue: per-token sigmoid/softmax/mask + log_prob.  (unchanged)
// ---------------------------------------------------------------------------
__global__ __launch_bounds__(256) void epilogue_kernel(
    const int* __restrict__ pY, const int* __restrict__ Yf,
    float* __restrict__ logp, float* __restrict__ mat)
{
  __shared__ float red[4];
  const int n = blockIdx.x;
  const int t = threadIdx.x;
  float* row = mat + (size_t)n * C_;
  const unsigned short* lg = (const unsigned short*)(row + 4);  // 2048 bf16

  const int py = pY[n];
  const int y  = Yf[n];

  // ---- read phase (row byte base is only 8B-aligned for odd n: uint2) -----
  uint2 p0 = *(const uint2*)(lg + (t << 3));
  uint2 p1 = *(const uint2*)(lg + (t << 3) + 4);
  const float z = row[0];
  const int ih = min(max(y - 2, 0), FP_ - 1);
  const int ir = min(max(y - 2 - FP_, 0), SP_ - 1);
  const float lh = bf2f(lg[ih]);          // same-address broadcast load
  const float lr = bf2f(lg[FP_ + ir]);

  // ---- exp + block sum (waves 0-1 -> Sh, waves 2-3 -> Sr) -----------------
  unsigned u[4] = {p0.x, p0.y, p1.x, p1.y};
  float e8[8];
  float s = 0.f;
#pragma unroll
  for (int i = 0; i < 4; ++i) {
    e8[2 * i]     = expf(bf2f((unsigned short)(u[i] & 0xffffu)));
    e8[2 * i + 1] = expf(bf2f((unsigned short)(u[i] >> 16)));
    s += e8[2 * i] + e8[2 * i + 1];
  }
#pragma unroll
  for (int o = 32; o; o >>= 1) s += __shfl_xor(s, o);
  const int w = t >> 6;
  if ((t & 63) == 0) red[w] = s;
  __syncthreads();   // also fences all reads above vs. in-place writes below
  const float Sh = red[0] + red[1];
  const float Sr = red[2] + red[3];

  // ---- write phase --------------------------------------------------------
  const float sig = 1.f / (1.f + expf(-z));
  const float ne  = 1.f - sig;
  const float sc = (t < 128) ? ((py == 1) ? ne / Sh : 0.f)
                             : ((py == 2) ? ne / Sr : 0.f);
  float2* wp = (float2*)(row + 2 + (t << 3));   // 8B-aligned
  wp[0] = make_float2(e8[0] * sc, e8[1] * sc);
  wp[1] = make_float2(e8[2] * sc, e8[3] * sc);
  wp[2] = make_float2(e8[4] * sc, e8[5] * sc);
  wp[3] = make_float2(e8[6] * sc, e8[7] * sc);
  if (t == 0) {
    const float ev = (py == 0) ? sig : 0.f;
    row[0] = ev;
    row[1] = ev;
    const float l1p   = log1pf(expf(-fabsf(z)));
    const float sp_z  = fmaxf(z, 0.f)  + l1p;
    const float sp_mz = fmaxf(-z, 0.f) + l1p;
    float lp;
    if      (py == 0) lp = -sp_mz;
    else if (py == 1) lp = (lh - logf(Sh)) - sp_z;
    else if (py == 2) lp = (lr - logf(Sr)) - sp_z;
    else              lp = 0.f;
    logp[n] = lp;
  }
}

// ---------------------------------------------------------------------------
extern "C" void kernel_launch(void* const* d_in, const int* in_sizes, int n_in,
                              void* d_out, int out_size, void* d_ws, size_t ws_size,
                              hipStream_t stream) {
  const float* X     = (const float*)d_in[0];
  const int*   pY    = (const int*)  d_in[1];
  const int*   Y     = (const int*)  d_in[2];
  const float* W_end = (const float*)d_in[3];
  const float* b_end = (const float*)d_in[4];
  const float* W_hcw = (const float*)d_in[5];
  const float* b_hcw = (const float*)d_in[6];
  const float* W_roo = (const float*)d_in[7];
  const float* b_roo = (const float*)d_in[8];

  float* out  = (float*)d_out;
  float* logp = out;              // [16384]
  float* mat  = out + N_TOK;      // [16384 x 2050], doubles as logit scratch

  const size_t xb_bytes = (size_t)N_TOK * H_ * 2;          // 67,108,864
  const size_t wb_bytes = (size_t)(FP_ + SP_) * H_ * 2;    //  8,388,608

  if (ws_size >= xb_bytes + wb_bytes) {
    unsigned short* Xb = (unsigned short*)d_ws;
    unsigned short* Wb = (unsigned short*)((char*)d_ws + xb_bytes);
    convert_kernel<<<(N_TOK + FP_ + SP_) / 4, 256, 0, stream>>>(
        X, W_hcw, W_roo, W_end, b_end, Xb, Wb, mat);
    dim3 g8(2048 / 256, N_TOK / 256);  // 8 x 64 = 512 blocks
    gemm_8phase_kernel<<<g8, 512, 0, stream>>>(Xb, Wb, b_hcw, b_roo, mat);
  } else {
    dim3 g(2048 / BN, N_TOK / BM);  // 16 x 128 blocks
    end_head_kernel<<<N_TOK / 4, 256, 0, stream>>>(X, W_end, b_end, mat);
    logits_gemm_fused<<<g, 256, 0, stream>>>(X, W_hcw, W_roo, b_hcw, b_roo, mat);
  }
  epilogue_kernel<<<N_TOK, 256, 0, stream>>>(pY, Y, logp, mat);
}

// Round 3
// 436.543 us; speedup vs baseline: 1.0249x; 1.0249x over previous
//
#include <hip/hip_runtime.h>
#include <hip/hip_bf16.h>
#include <cstddef>
#include <cstdint>

// Problem constants (fixed by the reference)
#define N_TOK 16384     // B*S = 32*512
#define H_    2048
#define FP_   1024
#define SP_   1024
#define C_    2050      // 2 + FP + SP, prob_all row stride

// Fallback-path tile (old 128^2 kernel, used only if ws too small)
#define BM 128
#define BN 128
#define BK 64
#define KP 72           // padded stride for the FALLBACK fused kernel only

typedef short bf16x8 __attribute__((ext_vector_type(8)));  // 8 bf16 = 4 VGPRs
typedef float f32x4  __attribute__((ext_vector_type(4)));  // 4 fp32 acc

__device__ __forceinline__ unsigned pack_bf2(float a, float b) {
  __hip_bfloat16 x = __float2bfloat16(a);
  __hip_bfloat16 y = __float2bfloat16(b);
  unsigned short ux, uy;
  __builtin_memcpy(&ux, &x, 2);
  __builtin_memcpy(&uy, &y, 2);
  return (unsigned)ux | ((unsigned)uy << 16);
}

__device__ __forceinline__ unsigned short f2bf(float f) {
  __hip_bfloat16 h = __float2bfloat16(f);
  unsigned short u;
  __builtin_memcpy(&u, &h, 2);
  return u;
}

__device__ __forceinline__ float bf2f(unsigned short u) {
  unsigned v = (unsigned)u << 16;
  float f;
  __builtin_memcpy(&f, &v, 4);
  return f;
}

// ---------------------------------------------------------------------------
// FAST PATH kernel 1: fp32 -> bf16 pre-convert of X (rows 0..16383) and
// W_hcw|W_roo (rows 16384..18431) into d_ws, fusing the end-head dot
// (fp32-exact) into the X pass. One wave per row, 4 rows/block.  (unchanged)
// ---------------------------------------------------------------------------
__global__ __launch_bounds__(256) void convert_kernel(
    const float* __restrict__ X,
    const float* __restrict__ W_hcw, const float* __restrict__ W_roo,
    const float* __restrict__ W_end, const float* __restrict__ b_end,
    unsigned short* __restrict__ Xb, unsigned short* __restrict__ Wb,
    float* __restrict__ mat)
{
  const int wave = threadIdx.x >> 6;
  const int lane = threadIdx.x & 63;
  const int row  = (blockIdx.x << 2) + wave;
  const bool isX = row < N_TOK;
  const float* src;
  unsigned short* dst;
  if (isX) {
    src = X + (size_t)row * H_;
    dst = Xb + (size_t)row * H_;
  } else {
    const int m = row - N_TOK;
    src = (m < FP_) ? (W_hcw + (size_t)m * H_) : (W_roo + (size_t)(m - FP_) * H_);
    dst = Wb + (size_t)m * H_;
  }
  float s = 0.f;
#pragma unroll
  for (int i = 0; i < 8; ++i) {
    const int e = (lane << 2) + (i << 8);      // lane*4 + i*256: coalesced
    float4 v = *(const float4*)(src + e);
    uint2 p;
    p.x = pack_bf2(v.x, v.y);
    p.y = pack_bf2(v.z, v.w);
    *(uint2*)(dst + e) = p;
    if (isX) {                                  // wave-uniform branch
      float4 w = *(const float4*)(W_end + e);
      s += v.x * w.x + v.y * w.y + v.z * w.z + v.w * w.w;
    }
  }
  if (isX) {
#pragma unroll
    for (int o = 32; o; o >>= 1) s += __shfl_xor(s, o);
    if (lane == 0) mat[(size_t)row * C_] = s + b_end[0];
  }
}

// ---------------------------------------------------------------------------
// FAST PATH kernel 2, round 3: 256x256 tile, BK=64, 8 waves (2Mx4N), with the
// FINE-INTERLEAVED 4-quadrant schedule (faithful T3+T4 port):
//
//   A-halves by fragment rows: AL = packed rows {0-63,128-191},
//                              AH = {64-127,192-255}  (per-wave i0-3 / i4-7)
//   B-halves by bit5 of class row: BL (j0-1), BH (j2-3)
//   Phase reads:  Q0=(AL,BL)  Q1=(AL,BH)  Q2=(AH,BH)  Q3=(AH,BL)
//
//   Staging of tile tk+1 (into buf[oth], NOT read this iteration):
//     top:  AL+BL (4 loads, issued BEFORE the wait)
//     Q0:   BH (2 loads)      Q1: AH (2 loads)
//   Iteration-top wait = vmcnt(4): retires exactly tile tk's 8 loads,
//   leaves tile tk+1's front-4 in flight -> NEVER drains in the main loop.
//
//   Packed LDS layout per buf: [h][pr][64] with pr&7 == l16&7 for all
//   fragment reads -> same conflict-free XOR chunk swizzle as before.
// ---------------------------------------------------------------------------
__global__ __launch_bounds__(512) void gemm_8phase_kernel(
    const unsigned short* __restrict__ Xb, const unsigned short* __restrict__ Wb,
    const float* __restrict__ b_hcw, const float* __restrict__ b_roo,
    float* __restrict__ mat)
{
  // [buf][ h*8192 + pr*64 + e ]  : 2 x 32 KB each
  __shared__ __align__(16) unsigned short As[2][2 * 128 * 64];
  __shared__ __align__(16) unsigned short Bs[2][2 * 128 * 64];

  const int c0 = blockIdx.x * 256;    // class-tile origin
  const int n0 = blockIdx.y * 256;    // token-tile origin
  const float* bias = (c0 < FP_) ? (b_hcw + c0) : (b_roo + (c0 - FP_));

  const int t    = threadIdx.x;       // 0..511
  const int wave = t >> 6;
  const int lane = t & 63;
  const int wr   = wave >> 2;         // 0..1 : M sub-tile (128 rows)
  const int wc   = wave & 3;          // 0..3 : N sub-tile (64 cols)
  const int quad = lane >> 4;
  const int l16  = lane & 15;
  const int sw   = l16 & 7;           // == packed_row&7 for all fragment rows

  // staging geometry: thread t covers packed row pr = s*64 + tA, chunk t&7;
  // slot (pr, pos) holds global chunk pos ^ (pr&7);  pr&7 == tA&7.
  const int tA   = t >> 3;                        // 0..63
  const int gofs = (((t & 7) ^ (tA & 7)) << 3);   // swizzled chunk (elements)
  const int ldst = tA * 64 + ((t & 7) << 3);      // LDS elems within 8KB sub
  const unsigned short* gA0 = Xb + (size_t)n0 * H_ + gofs;
  const unsigned short* gB0 = Wb + (size_t)c0 * H_ + gofs;
  // B global row for (h,s): s*128 + h*32 + (tA>>5)*64 + (tA&31)
  const int growB = ((tA >> 5) << 6) + (tA & 31);

  auto stageA = [&](int buf, int h, int s, int k0) {
    __builtin_amdgcn_global_load_lds(
        (const __attribute__((address_space(1))) unsigned int*)
            (gA0 + (size_t)(s * 128 + h * 64 + tA) * H_ + k0),
        (__attribute__((address_space(3))) unsigned int*)
            (&As[buf][h * 8192 + s * 4096 + ldst]),
        16, 0, 0);
  };
  auto stageB = [&](int buf, int h, int s, int k0) {
    __builtin_amdgcn_global_load_lds(
        (const __attribute__((address_space(1))) unsigned int*)
            (gB0 + (size_t)(s * 128 + h * 32 + growB) * H_ + k0),
        (__attribute__((address_space(3))) unsigned int*)
            (&Bs[buf][h * 8192 + s * 4096 + ldst]),
        16, 0, 0);
  };

  f32x4 acc[8][4];
#pragma unroll
  for (int i = 0; i < 8; ++i)
#pragma unroll
    for (int j = 0; j < 4; ++j)
#pragma unroll
      for (int r = 0; r < 4; ++r) acc[i][j][r] = 0.f;

  // fragment LDS row bases (packed): A: wr*64 + i*16 + l16 (i local 0..3)
  //                                  B: wc*32 + j*16 + l16 (j local 0..1)
  const int aprow = wr * 64 + l16;
  const int bprow = wc * 32 + l16;

  // prologue: tile 0 fully staged (mimics steady-state issue order)
  stageA(0, 0, 0, 0); stageA(0, 0, 1, 0);   // AL(0)
  stageB(0, 0, 0, 0); stageB(0, 0, 1, 0);   // BL(0)
  stageB(0, 1, 0, 0); stageB(0, 1, 1, 0);   // BH(0)
  stageA(0, 1, 0, 0); stageA(0, 1, 1, 0);   // AH(0)

  bf16x8 a[4][2], b[2][2];

#pragma unroll 1
  for (int tk = 0; tk < 32; ++tk) {
    const int cur = tk & 1;
    const int oth = cur ^ 1;
    const int kN  = (tk + 1) << 6;

    // ---- iteration top: front-load AL,BL of tile tk+1; counted wait -------
    if (tk < 31) {
      stageA(oth, 0, 0, kN); stageA(oth, 0, 1, kN);
      stageB(oth, 0, 0, kN); stageB(oth, 0, 1, kN);
      asm volatile("s_waitcnt vmcnt(4)" ::: "memory");   // tile tk retired
    } else {
      asm volatile("s_waitcnt vmcnt(0)" ::: "memory");   // last tile: drain
    }
    __builtin_amdgcn_sched_barrier(0);
    __builtin_amdgcn_s_barrier();

    const unsigned short* A_ = &As[cur][0];
    const unsigned short* B_ = &Bs[cur][0];

    // ---- Q0: read AL frags + BL frags; stage BH(tk+1); MFMA iL x jL -------
#pragma unroll
    for (int i = 0; i < 4; ++i)
#pragma unroll
      for (int kk = 0; kk < 2; ++kk)
        a[i][kk] = *(const bf16x8*)&A_[(aprow + i * 16) * 64 + ((((kk << 2) + quad) ^ sw) << 3)];
#pragma unroll
    for (int j = 0; j < 2; ++j)
#pragma unroll
      for (int kk = 0; kk < 2; ++kk)
        b[j][kk] = *(const bf16x8*)&B_[(bprow + j * 16) * 64 + ((((kk << 2) + quad) ^ sw) << 3)];
    if (tk < 31) { stageB(oth, 1, 0, kN); stageB(oth, 1, 1, kN); }
    __builtin_amdgcn_s_barrier();
    asm volatile("s_waitcnt lgkmcnt(0)" ::: "memory");
    __builtin_amdgcn_sched_barrier(0);
    __builtin_amdgcn_s_setprio(1);
#pragma unroll
    for (int i = 0; i < 4; ++i)
#pragma unroll
      for (int j = 0; j < 2; ++j)
#pragma unroll
        for (int kk = 0; kk < 2; ++kk)
          acc[i][j] = __builtin_amdgcn_mfma_f32_16x16x32_bf16(a[i][kk], b[j][kk], acc[i][j], 0, 0, 0);
    __builtin_amdgcn_s_setprio(0);
    __builtin_amdgcn_s_barrier();

    // ---- Q1: read BH frags; stage AH(tk+1); MFMA iL x jH ------------------
#pragma unroll
    for (int j = 0; j < 2; ++j)
#pragma unroll
      for (int kk = 0; kk < 2; ++kk)
        b[j][kk] = *(const bf16x8*)&B_[8192 + (bprow + j * 16) * 64 + ((((kk << 2) + quad) ^ sw) << 3)];
    if (tk < 31) { stageA(oth, 1, 0, kN); stageA(oth, 1, 1, kN); }
    __builtin_amdgcn_s_barrier();
    asm volatile("s_waitcnt lgkmcnt(0)" ::: "memory");
    __builtin_amdgcn_sched_barrier(0);
    __builtin_amdgcn_s_setprio(1);
#pragma unroll
    for (int i = 0; i < 4; ++i)
#pragma unroll
      for (int j = 0; j < 2; ++j)
#pragma unroll
        for (int kk = 0; kk < 2; ++kk)
          acc[i][j + 2] = __builtin_amdgcn_mfma_f32_16x16x32_bf16(a[i][kk], b[j][kk], acc[i][j + 2], 0, 0, 0);
    __builtin_amdgcn_s_setprio(0);
    __builtin_amdgcn_s_barrier();

    // ---- Q2: read AH frags; MFMA iH x jH ----------------------------------
#pragma unroll
    for (int i = 0; i < 4; ++i)
#pragma unroll
      for (int kk = 0; kk < 2; ++kk)
        a[i][kk] = *(const bf16x8*)&A_[8192 + (aprow + i * 16) * 64 + ((((kk << 2) + quad) ^ sw) << 3)];
    __builtin_amdgcn_s_barrier();
    asm volatile("s_waitcnt lgkmcnt(0)" ::: "memory");
    __builtin_amdgcn_sched_barrier(0);
    __builtin_amdgcn_s_setprio(1);
#pragma unroll
    for (int i = 0; i < 4; ++i)
#pragma unroll
      for (int j = 0; j < 2; ++j)
#pragma unroll
        for (int kk = 0; kk < 2; ++kk)
          acc[i + 4][j + 2] = __builtin_amdgcn_mfma_f32_16x16x32_bf16(a[i][kk], b[j][kk], acc[i + 4][j + 2], 0, 0, 0);
    __builtin_amdgcn_s_setprio(0);
    __builtin_amdgcn_s_barrier();

    // ---- Q3: read BL frags again; MFMA iH x jL ----------------------------
#pragma unroll
    for (int j = 0; j < 2; ++j)
#pragma unroll
      for (int kk = 0; kk < 2; ++kk)
        b[j][kk] = *(const bf16x8*)&B_[(bprow + j * 16) * 64 + ((((kk << 2) + quad) ^ sw) << 3)];
    __builtin_amdgcn_s_barrier();
    asm volatile("s_waitcnt lgkmcnt(0)" ::: "memory");
    __builtin_amdgcn_sched_barrier(0);
    __builtin_amdgcn_s_setprio(1);
#pragma unroll
    for (int i = 0; i < 4; ++i)
#pragma unroll
      for (int j = 0; j < 2; ++j)
#pragma unroll
        for (int kk = 0; kk < 2; ++kk)
          acc[i + 4][j] = __builtin_amdgcn_mfma_f32_16x16x32_bf16(a[i][kk], b[j][kk], acc[i + 4][j], 0, 0, 0);
    __builtin_amdgcn_s_setprio(0);
    __builtin_amdgcn_s_barrier();   // all reads of buf[cur] retired
  }

  // C/D layout: col=lane&15, row=quad*4+reg (m89-verified). Store bf16.
  float bj[4];
#pragma unroll
  for (int j = 0; j < 4; ++j) bj[j] = bias[wc * 64 + j * 16 + l16];
#pragma unroll
  for (int i = 0; i < 8; ++i) {
#pragma unroll
    for (int r = 0; r < 4; ++r) {
      const int row = n0 + wr * 128 + i * 16 + quad * 4 + r;
      unsigned short* dst =
          (unsigned short*)(mat + (size_t)row * C_ + 4) + c0 + wc * 64 + l16;
#pragma unroll
      for (int j = 0; j < 4; ++j) dst[j * 16] = f2bf(acc[i][j][r] + bj[j]);
    }
  }
}

// ---------------------------------------------------------------------------
// FALLBACK kernels (used only if ws_size is too small). Same bf16-logit
// output convention as the fast path so one epilogue serves both.
// ---------------------------------------------------------------------------
__global__ __launch_bounds__(256) void end_head_kernel(
    const float* __restrict__ X, const float* __restrict__ W_end,
    const float* __restrict__ b_end, float* __restrict__ mat)
{
  const int wave = threadIdx.x >> 6;
  const int lane = threadIdx.x & 63;
  const int n = (blockIdx.x << 2) + wave;
  const float* x = X + (size_t)n * H_;
  float s = 0.f;
#pragma unroll
  for (int i = 0; i < 8; ++i) {
    const int e = (lane + (i << 6)) << 2;
    float4 xv = *(const float4*)(x + e);
    float4 wv = *(const float4*)(W_end + e);
    s += xv.x * wv.x + xv.y * wv.y + xv.z * wv.z + xv.w * wv.w;
  }
#pragma unroll
  for (int o = 32; o; o >>= 1) s += __shfl_xor(s, o);
  if (lane == 0) mat[(size_t)n * C_] = s + b_end[0];
}

__global__ __launch_bounds__(256) void logits_gemm_fused(
    const float* __restrict__ X,
    const float* __restrict__ W_hcw, const float* __restrict__ W_roo,
    const float* __restrict__ b_hcw, const float* __restrict__ b_roo,
    float* __restrict__ mat)
{
  __shared__ __align__(16) unsigned short As[BM * KP];
  __shared__ __align__(16) unsigned short Bs[BN * KP];

  const int c0 = blockIdx.x * BN;
  const int n0 = blockIdx.y * BM;
  const float* Wbase = (c0 < FP_) ? (W_hcw + (size_t)c0 * H_)
                                  : (W_roo + (size_t)(c0 - FP_) * H_);
  const float* bias  = (c0 < FP_) ? (b_hcw + c0) : (b_roo + (c0 - FP_));

  const int t    = threadIdx.x;
  const int wave = t >> 6;
  const int lane = t & 63;
  const int wy   = wave >> 1;
  const int wx   = wave & 1;
  const int quad = lane >> 4;
  const int l16  = lane & 15;
  const int tq = t & 3;
  const int tr = t >> 2;

  f32x4 acc[4][4];
#pragma unroll
  for (int i = 0; i < 4; ++i)
#pragma unroll
    for (int j = 0; j < 4; ++j)
#pragma unroll
      for (int r = 0; r < 4; ++r) acc[i][j][r] = 0.f;

  for (int k0 = 0; k0 < H_; k0 += BK) {
#pragma unroll
    for (int p = 0; p < 2; ++p) {
      const int row = tr + (p << 6);
      const float4* xs = (const float4*)(X + (size_t)(n0 + row) * H_ + k0 + (tq << 4));
      const float4* ws = (const float4*)(Wbase + (size_t)row * H_ + k0 + (tq << 4));
      float4 x0 = xs[0], x1 = xs[1], x2 = xs[2], x3 = xs[3];
      float4 w0 = ws[0], w1 = ws[1], w2 = ws[2], w3 = ws[3];
      uint4 ua0 = {pack_bf2(x0.x, x0.y), pack_bf2(x0.z, x0.w),
                   pack_bf2(x1.x, x1.y), pack_bf2(x1.z, x1.w)};
      uint4 ua1 = {pack_bf2(x2.x, x2.y), pack_bf2(x2.z, x2.w),
                   pack_bf2(x3.x, x3.y), pack_bf2(x3.z, x3.w)};
      uint4 ub0 = {pack_bf2(w0.x, w0.y), pack_bf2(w0.z, w0.w),
                   pack_bf2(w1.x, w1.y), pack_bf2(w1.z, w1.w)};
      uint4 ub1 = {pack_bf2(w2.x, w2.y), pack_bf2(w2.z, w2.w),
                   pack_bf2(w3.x, w3.y), pack_bf2(w3.z, w3.w)};
      *(uint4*)&As[row * KP + (tq << 4)]     = ua0;
      *(uint4*)&As[row * KP + (tq << 4) + 8] = ua1;
      *(uint4*)&Bs[row * KP + (tq << 4)]     = ub0;
      *(uint4*)&Bs[row * KP + (tq << 4) + 8] = ub1;
    }
    __syncthreads();
#pragma unroll
    for (int kk = 0; kk < 2; ++kk) {
      bf16x8 af[4], bfr[4];
#pragma unroll
      for (int i = 0; i < 4; ++i)
        af[i] = *(const bf16x8*)&As[(wy * 64 + i * 16 + l16) * KP + kk * 32 + quad * 8];
#pragma unroll
      for (int j = 0; j < 4; ++j)
        bfr[j] = *(const bf16x8*)&Bs[(wx * 64 + j * 16 + l16) * KP + kk * 32 + quad * 8];
#pragma unroll
      for (int i = 0; i < 4; ++i)
#pragma unroll
        for (int j = 0; j < 4; ++j)
          acc[i][j] = __builtin_amdgcn_mfma_f32_16x16x32_bf16(af[i], bfr[j], acc[i][j], 0, 0, 0);
    }
    __syncthreads();
  }

  float bj[4];
#pragma unroll
  for (int j = 0; j < 4; ++j) bj[j] = bias[wx * 64 + j * 16 + l16];
#pragma unroll
  for (int i = 0; i < 4; ++i) {
#pragma unroll
    for (int r = 0; r < 4; ++r) {
      const int row = n0 + wy * 64 + i * 16 + quad * 4 + r;
      unsigned short* dst =
          (unsigned short*)(mat + (size_t)row * C_ + 4) + c0 + wx * 64 + l16;
#pragma unroll
      for (int j = 0; j < 4; ++j) dst[j * 16] = f2bf(acc[i][j][r] + bj[j]);
    }
  }
}

// ---------------------------------------------------------------------------
// Epilogue: per-token sigmoid/softmax/mask + log_prob.  (unchanged)
// ---------------------------------------------------------------------------
__global__ __launch_bounds__(256) void epilogue_kernel(
    const int* __restrict__ pY, const int* __restrict__ Yf,
    float* __restrict__ logp, float* __restrict__ mat)
{
  __shared__ float red[4];
  const int n = blockIdx.x;
  const int t = threadIdx.x;
  float* row = mat + (size_t)n * C_;
  const unsigned short* lg = (const unsigned short*)(row + 4);  // 2048 bf16

  const int py = pY[n];
  const int y  = Yf[n];

  // ---- read phase (row byte base is only 8B-aligned for odd n: uint2) -----
  uint2 p0 = *(const uint2*)(lg + (t << 3));
  uint2 p1 = *(const uint2*)(lg + (t << 3) + 4);
  const float z = row[0];
  const int ih = min(max(y - 2, 0), FP_ - 1);
  const int ir = min(max(y - 2 - FP_, 0), SP_ - 1);
  const float lh = bf2f(lg[ih]);          // same-address broadcast load
  const float lr = bf2f(lg[FP_ + ir]);

  // ---- exp + block sum (waves 0-1 -> Sh, waves 2-3 -> Sr) -----------------
  unsigned u[4] = {p0.x, p0.y, p1.x, p1.y};
  float e8[8];
  float s = 0.f;
#pragma unroll
  for (int i = 0; i < 4; ++i) {
    e8[2 * i]     = expf(bf2f((unsigned short)(u[i] & 0xffffu)));
    e8[2 * i + 1] = expf(bf2f((unsigned short)(u[i] >> 16)));
    s += e8[2 * i] + e8[2 * i + 1];
  }
#pragma unroll
  for (int o = 32; o; o >>= 1) s += __shfl_xor(s, o);
  const int w = t >> 6;
  if ((t & 63) == 0) red[w] = s;
  __syncthreads();   // also fences all reads above vs. in-place writes below
  const float Sh = red[0] + red[1];
  const float Sr = red[2] + red[3];

  // ---- write phase --------------------------------------------------------
  const float sig = 1.f / (1.f + expf(-z));
  const float ne  = 1.f - sig;
  const float sc = (t < 128) ? ((py == 1) ? ne / Sh : 0.f)
                             : ((py == 2) ? ne / Sr : 0.f);
  float2* wp = (float2*)(row + 2 + (t << 3));   // 8B-aligned
  wp[0] = make_float2(e8[0] * sc, e8[1] * sc);
  wp[1] = make_float2(e8[2] * sc, e8[3] * sc);
  wp[2] = make_float2(e8[4] * sc, e8[5] * sc);
  wp[3] = make_float2(e8[6] * sc, e8[7] * sc);
  if (t == 0) {
    const float ev = (py == 0) ? sig : 0.f;
    row[0] = ev;
    row[1] = ev;
    const float l1p   = log1pf(expf(-fabsf(z)));
    const float sp_z  = fmaxf(z, 0.f)  + l1p;
    const float sp_mz = fmaxf(-z, 0.f) + l1p;
    float lp;
    if      (py == 0) lp = -sp_mz;
    else if (py == 1) lp = (lh - logf(Sh)) - sp_z;
    else if (py == 2) lp = (lr - logf(Sr)) - sp_z;
    else              lp = 0.f;
    logp[n] = lp;
  }
}

// ---------------------------------------------------------------------------
extern "C" void kernel_launch(void* const* d_in, const int* in_sizes, int n_in,
                              void* d_out, int out_size, void* d_ws, size_t ws_size,
                              hipStream_t stream) {
  const float* X     = (const float*)d_in[0];
  const int*   pY    = (const int*)  d_in[1];
  const int*   Y     = (const int*)  d_in[2];
  const float* W_end = (const float*)d_in[3];
  const float* b_end = (const float*)d_in[4];
  const float* W_hcw = (const float*)d_in[5];
  const float* b_hcw = (const float*)d_in[6];
  const float* W_roo = (const float*)d_in[7];
  const float* b_roo = (const float*)d_in[8];

  float* out  = (float*)d_out;
  float* logp = out;              // [16384]
  float* mat  = out + N_TOK;      // [16384 x 2050], doubles as logit scratch

  const size_t xb_bytes = (size_t)N_TOK * H_ * 2;          // 67,108,864
  const size_t wb_bytes = (size_t)(FP_ + SP_) * H_ * 2;    //  8,388,608

  if (ws_size >= xb_bytes + wb_bytes) {
    unsigned short* Xb = (unsigned short*)d_ws;
    unsigned short* Wb = (unsigned short*)((char*)d_ws + xb_bytes);
    convert_kernel<<<(N_TOK + FP_ + SP_) / 4, 256, 0, stream>>>(
        X, W_hcw, W_roo, W_end, b_end, Xb, Wb, mat);
    dim3 g8(2048 / 256, N_TOK / 256);  // 8 x 64 = 512 blocks
    gemm_8phase_kernel<<<g8, 512, 0, stream>>>(Xb, Wb, b_hcw, b_roo, mat);
  } else {
    dim3 g(2048 / BN, N_TOK / BM);  // 16 x 128 blocks
    end_head_kernel<<<N_TOK / 4, 256, 0, stream>>>(X, W_end, b_end, mat);
    logits_gemm_fused<<<g, 256, 0, stream>>>(X, W_hcw, W_roo, b_hcw, b_roo, mat);
  }
  epilogue_kernel<<<N_TOK, 256, 0, stream>>>(pY, Y, logp, mat);
}